// Round 5
// baseline (1353.511 us; speedup 1.0000x reference)
//
#include <hip/hip_runtime.h>
#include <stdint.h>

// BitLinear on MI355X: per-token int8 activation quant + per-tensor ternary
// weight quant + exact int8 MFMA GEMM.
//
// GEMM: 256x256 tile, 8 waves, quad-buffered K-tiles (KT=64), single-barrier
// merged-region schedule with 32x32x32 i8 MFMA, counted vmcnt(8), race-free
// t+3 staging, LDS XOR swizzle via pre-swizzled global source, XCD swizzle.

typedef int v4i  __attribute__((ext_vector_type(4)));
typedef int v16i __attribute__((ext_vector_type(16)));

#define QEPS 1e-5f

#define M_DIM 8192
#define N_DIM 16384
#define K_DIM 4096

// ---------------- Kernel 1: sum of |w| (double accumulate) ----------------
__global__ void wabs_sum(const float* __restrict__ w, double* __restrict__ acc,
                         int n4) {
    int idx = blockIdx.x * blockDim.x + threadIdx.x;
    int stride = gridDim.x * blockDim.x;
    const float4* w4 = (const float4*)w;
    double s = 0.0;
    for (int i = idx; i < n4; i += stride) {
        float4 v = w4[i];
        s += (double)(fabsf(v.x) + fabsf(v.y) + fabsf(v.z) + fabsf(v.w));
    }
    #pragma unroll
    for (int off = 32; off > 0; off >>= 1)
        s += __shfl_down(s, off, 64);
    __shared__ double sm[4];
    int lane = threadIdx.x & 63, wv = threadIdx.x >> 6;
    if (lane == 0) sm[wv] = s;
    __syncthreads();
    if (threadIdx.x == 0) {
        atomicAdd(acc, sm[0] + sm[1] + sm[2] + sm[3]);
    }
}

// ---------------- Kernel 2: ternary weight quant ----------------
__device__ __forceinline__ int tq1(float v, float s) {
    float q = rintf(v * s);
    q = fminf(fmaxf(q, -1.0f), 1.0f);
    return (int)q;
}

__global__ void wquant(const float* __restrict__ w, int8_t* __restrict__ tw,
                       const double* __restrict__ acc, double inv_cnt, int n4) {
    double mean = (*acc) * inv_cnt;
    float mclip = (float)fmax(mean, (double)QEPS);
    float sw = 1.0f / mclip;
    int idx = blockIdx.x * blockDim.x + threadIdx.x;
    int stride = gridDim.x * blockDim.x;
    const float4* w4 = (const float4*)w;
    uint32_t* out = (uint32_t*)tw;
    for (int i = idx; i < n4; i += stride) {
        float4 v = w4[i];
        uint32_t a = (uint32_t)(tq1(v.x, sw) & 0xff);
        uint32_t b = (uint32_t)(tq1(v.y, sw) & 0xff);
        uint32_t c = (uint32_t)(tq1(v.z, sw) & 0xff);
        uint32_t d = (uint32_t)(tq1(v.w, sw) & 0xff);
        out[i] = a | (b << 8) | (c << 16) | (d << 24);
    }
}

// ---------------- Kernel 3: per-token int8 activation quant ----------------
__device__ __forceinline__ int q8(float v, float s) {
    float q = rintf(v * s);
    q = fminf(fmaxf(q, -128.0f), 127.0f);
    return (int)q;
}

__global__ void xquant(const float* __restrict__ x, int8_t* __restrict__ qx,
                       float* __restrict__ rowscale) {
    int row = blockIdx.x;
    int t = threadIdx.x;
    const float4* xr = (const float4*)(x + (size_t)row * K_DIM);
    float4 v[4];
    float m = 0.0f;
    #pragma unroll
    for (int i = 0; i < 4; i++) {
        v[i] = xr[t + i * 256];
        m = fmaxf(m, fmaxf(fmaxf(fabsf(v[i].x), fabsf(v[i].y)),
                           fmaxf(fabsf(v[i].z), fabsf(v[i].w))));
    }
    #pragma unroll
    for (int off = 32; off > 0; off >>= 1)
        m = fmaxf(m, __shfl_down(m, off, 64));
    __shared__ float sm[4];
    int lane = t & 63, wv = t >> 6;
    if (lane == 0) sm[wv] = m;
    __syncthreads();
    m = fmaxf(fmaxf(sm[0], sm[1]), fmaxf(sm[2], sm[3]));
    float mc = fmaxf(m, QEPS);
    float scale = 127.0f / mc;
    if (t == 0) rowscale[row] = mc * (1.0f / 127.0f);
    uint32_t* qr = (uint32_t*)(qx + (size_t)row * K_DIM);
    #pragma unroll
    for (int i = 0; i < 4; i++) {
        uint32_t a = (uint32_t)(q8(v[i].x, scale) & 0xff);
        uint32_t b = (uint32_t)(q8(v[i].y, scale) & 0xff);
        uint32_t c = (uint32_t)(q8(v[i].z, scale) & 0xff);
        uint32_t d = (uint32_t)(q8(v[i].w, scale) & 0xff);
        qr[t + i * 256] = a | (b << 8) | (c << 16) | (d << 24);
    }
}

// ---------------- Kernel 4: int8 MFMA GEMM, 32x32x32 merged-region --------
// Geometry: BM=BN=256, KT=64, NT=64 tiles. 512 threads = 8 waves (2M x 4N);
// per-wave output 128x64 = 4mb x 2nb fragments of mfma_i32_32x32x32_i8,
// K=64 -> 2 MFMA per fragment = 16 MFMA/tile/wave. LDS: 4 slots per operand
// (tile t -> slot t&3), slot = 256 rows x 64 B = 16 KB; 128 KiB total.
//
// Per tile t (ONE inter-barrier region, no setprio fence inside so the
// compiler interleaves ds_read service under MFMAs with counted lgkmcnt):
//   [12 x ds_read_b128 | stage A(t+3),B(t+3) | 16 MFMA] vmcnt(N) s_barrier
//
// Staging at t+3 writes slot (t+3)&3 = (t-1)&3, whose last reads completed
// before the PREVIOUS barrier -> no write-vs-read race (unlike t+4 scheme).
// vmcnt ledger (4 loads/tile staged): prologue stages tiles 0,1,2 (12 loads).
// At end-of-tile-t wait, issued = 12+4(t+1) (t<=60); need tile t+1 complete
// = first 8+4t loads -> N = 8 steady-state; tail 4 -> 0.
//
// LDS swizzle (unchanged, verified conflict-free in R4: SQ_LDS_BANK_CONFLICT
// = 0): read addr byte ^= ((row>>1)&3)<<4; global source column pre-swizzled
// with the same involution since global_load_lds writes base+lane*16.

#define BM 256
#define BN 256
#define KT 64
#define SLOT 16384

__device__ __forceinline__ void async_copy16(const void* g, void* l) {
    __builtin_amdgcn_global_load_lds(
        (__attribute__((address_space(1))) void*)g,
        (__attribute__((address_space(3))) void*)l, 16, 0, 0);
}

#define WAITVM_IMM(N) asm volatile("s_waitcnt vmcnt(" #N ")" ::: "memory")
#define WAITVM(N) WAITVM_IMM(N)
#define BAR() __builtin_amdgcn_s_barrier()

__global__ __launch_bounds__(512, 2)
void gemm_i8(const int8_t* __restrict__ A,   // [M][K] int8
             const int8_t* __restrict__ B,   // [N][K] ternary int8
             const float* __restrict__ rowscale,
             const double* __restrict__ macc, double inv_cnt,
             float* __restrict__ C) {
    __shared__ int8_t As[4][SLOT];
    __shared__ int8_t Bs[4][SLOT];

    const int tid = threadIdx.x;
    const int wave = tid >> 6;
    const int lane = tid & 63;

    // XCD-aware bijective swizzle: 2048 blocks, 8 XCDs, 256 each; bn fastest.
    const int orig = blockIdx.x;
    const int idx = (orig & 7) * 256 + (orig >> 3);
    const int bm = (idx >> 6) * BM;   // 32 block-rows
    const int bn = (idx & 63) * BN;   // 64 block-cols

    const int wr  = wave >> 2;   // 0..1  (M side)
    const int wc  = wave & 3;    // 0..3  (N side)
    const int l31 = lane & 31;   // fragment row within 32-row block
    const int h   = lane >> 5;   // k-sub-quarter selector

    // swizzled ds_read offsets: row-bases are multiples of 32, so
    // (row>>1)&3 == (l31>>1)&3, constant per lane.
    const int swz = (l31 >> 1) & 3;
    const int c16[2] = { ((0 * 2 + h) ^ swz) << 4, ((1 * 2 + h) ^ swz) << 4 };
    const int aoff0 = (wr * 128 + l31) * 64;   // + mb*2048 + c16[kh]
    const int boff0 = (wc * 64 + l31) * 64;    // + nb*2048 + c16[kh]

    // staging: 2 issues/thread/operand; chunk = issue*8+wave covers rows
    // chunk*16..+15; LDS dest linear; global source column pre-swizzled.
    const int l2   = lane >> 2;
    const int gcol = ((lane & 3) ^ ((lane >> 3) & 3)) << 4;
    const int c0   = wave;
    const int c1   = 8 + wave;
    const int8_t* aS0 = A + (size_t)(bm + c0 * 16 + l2) * K_DIM + gcol;
    const int8_t* aS1 = A + (size_t)(bm + c1 * 16 + l2) * K_DIM + gcol;
    const int8_t* bS0 = B + (size_t)(bn + c0 * 16 + l2) * K_DIM + gcol;
    const int8_t* bS1 = B + (size_t)(bn + c1 * 16 + l2) * K_DIM + gcol;

    v16i acc[4][2] = {};

#define STAGE_A(T) do { const int _s = (T) & 3; const int _k = (T) * KT;    \
        async_copy16(aS0 + _k, &As[_s][c0 * 1024]);                         \
        async_copy16(aS1 + _k, &As[_s][c1 * 1024]); } while (0)
#define STAGE_B(T) do { const int _s = (T) & 3; const int _k = (T) * KT;    \
        async_copy16(bS0 + _k, &Bs[_s][c0 * 1024]);                         \
        async_copy16(bS1 + _k, &Bs[_s][c1 * 1024]); } while (0)

#define TILE(T, DOSTAGE) do {                                               \
        const int8_t* _as = As[(T) & 3];                                    \
        const int8_t* _bs = Bs[(T) & 3];                                    \
        v4i ta[4][2], tb[2][2];                                             \
        _Pragma("unroll")                                                   \
        for (int mb = 0; mb < 4; mb++) {                                    \
            _Pragma("unroll")                                               \
            for (int kh = 0; kh < 2; kh++)                                  \
                ta[mb][kh] =                                                \
                    *(const v4i*)(_as + aoff0 + mb * 2048 + c16[kh]);       \
        }                                                                   \
        _Pragma("unroll")                                                   \
        for (int nb = 0; nb < 2; nb++) {                                    \
            _Pragma("unroll")                                               \
            for (int kh = 0; kh < 2; kh++)                                  \
                tb[nb][kh] =                                                \
                    *(const v4i*)(_bs + boff0 + nb * 2048 + c16[kh]);       \
        }                                                                   \
        if (DOSTAGE) { STAGE_A((T) + 3); STAGE_B((T) + 3); }                \
        _Pragma("unroll")                                                   \
        for (int mb = 0; mb < 4; mb++) {                                    \
            _Pragma("unroll")                                               \
            for (int nb = 0; nb < 2; nb++) {                                \
                _Pragma("unroll")                                           \
                for (int kh = 0; kh < 2; kh++)                              \
                    acc[mb][nb] = __builtin_amdgcn_mfma_i32_32x32x32_i8(    \
                        ta[mb][kh], tb[nb][kh], acc[mb][nb], 0, 0, 0);      \
            }                                                               \
        }                                                                   \
    } while (0)

    // Prologue: stage tiles 0,1,2 (12 loads); vmcnt(8) completes tile 0.
    STAGE_A(0); STAGE_B(0); STAGE_A(1); STAGE_B(1); STAGE_A(2); STAGE_B(2);
    WAITVM(8);
    BAR();

    // Main loop: unroll x4 keeps slot index static.
    for (int t4 = 0; t4 < 60; t4 += 4) {
        TILE(t4 + 0, 1); WAITVM(8); BAR();
        TILE(t4 + 1, 1); WAITVM(8); BAR();
        TILE(t4 + 2, 1); WAITVM(8); BAR();
        TILE(t4 + 3, 1); WAITVM(8); BAR();
    }
    // Tail: t=60 stages tile 63; waits drain 8 -> 4 -> 0.
    TILE(60, 1); WAITVM(8); BAR();
    TILE(61, 0); WAITVM(4); BAR();
    TILE(62, 0); WAITVM(0); BAR();
    TILE(63, 0);

    // Epilogue: 32x32 C/D layout col=lane&31, row=(reg&3)+8*(reg>>2)+4*h.
    float mw = (float)fmax((*macc) * inv_cnt, (double)QEPS);
    const int col0 = bn + wc * 64 + l31;
    #pragma unroll
    for (int mb = 0; mb < 4; mb++) {
        #pragma unroll
        for (int rg = 0; rg < 16; rg++) {
            const int row = bm + wr * 128 + mb * 32 +
                            (rg & 3) + 8 * (rg >> 2) + 4 * h;
            const float rs = rowscale[row] * mw;
            float* crow = C + (size_t)row * N_DIM;
            #pragma unroll
            for (int nb = 0; nb < 2; nb++) {
                crow[col0 + nb * 32] = (float)acc[mb][nb][rg] * rs;
            }
        }
    }
}

// ---------------- launch ----------------
extern "C" void kernel_launch(void* const* d_in, const int* in_sizes, int n_in,
                              void* d_out, int out_size, void* d_ws,
                              size_t ws_size, hipStream_t stream) {
    const float* x = (const float*)d_in[0];
    const float* w = (const float*)d_in[1];
    float* out = (float*)d_out;

    const size_t QX_BYTES = (size_t)M_DIM * K_DIM;        // 33554432
    const size_t TW_BYTES = (size_t)N_DIM * K_DIM;        // 67108864
    int8_t* qx = (int8_t*)d_ws;
    int8_t* tw = (int8_t*)d_ws + QX_BYTES;
    float* rowscale = (float*)((char*)d_ws + QX_BYTES + TW_BYTES);
    double* macc = (double*)((char*)d_ws + QX_BYTES + TW_BYTES +
                             (size_t)M_DIM * sizeof(float));

    const double inv_cnt = 1.0 / (double)((size_t)N_DIM * K_DIM);

    (void)hipMemsetAsync(macc, 0, sizeof(double), stream);
    wabs_sum<<<1024, 256, 0, stream>>>(w, macc, (N_DIM * K_DIM) / 4);
    wquant<<<2048, 256, 0, stream>>>(w, tw, macc, inv_cnt, (N_DIM * K_DIM) / 4);
    xquant<<<M_DIM, 256, 0, stream>>>(x, qx, rowscale);
    gemm_i8<<<2048, 512, 0, stream>>>(qx, tw, rowscale, macc, inv_cnt, out);
}